// Round 22
// baseline (128.483 us; speedup 1.0000x reference)
//
#include <hip/hip_runtime.h>

// GCN 2-layer, fully-deterministic two-level sort + register aggregation.
// History: global fp32 atomics EA-bound (r1-2); bucket sort + LDS atomics
// (r5-14); two-level sort + lane-per-node register agg (r15-20, 127us).
// Round-21: (1) uint4 vectorized dst/src loads in part_hist & scatter
// (16B-aligned by construction: chunk starts are multiples of 8192, E*4
// divisible by 16); (2) sort2 single-global-read: stage into LDS buf during
// the count pass, place buf->buf2 in LDS, coalesced stream-out (~138KB LDS,
// grid 391 on 256 CUs so the 1-block/CU cap is mostly immaterial).
// All buffers remain pure functions of the inputs (replay-deterministic).
// (r21 submission never ran -- infra push failure; identical resubmit.)

typedef unsigned int u32;
typedef unsigned short u16;

#define BUCKET_BITS 9
#define BUCKET_SIZE (1 << BUCKET_BITS)   // 512 nodes per bucket
#define MAX_NBUCK 512                    // supports N <= 262144
#define PCHUNK 8192                      // edges per partition chunk
#define BT 1024                          // big-block threads
#define MAX_NB 1024                      // supports E <= 8.4M
#define LDSCAP 17408                     // max edges staged per bucket (68KB)

// K1: per-chunk bucket histogram -> part[c*nbuck + j]  (uint4 loads)
__global__ void __launch_bounds__(BT)
part_hist_kernel(const int* __restrict__ dst, u32* __restrict__ part,
                 int E, int nbuck) {
    __shared__ u32 h[MAX_NBUCK];
    int t = threadIdx.x, c = blockIdx.x;
    if (t < MAX_NBUCK) h[t] = 0;
    __syncthreads();
    int start = c * PCHUNK, end = min(start + PCHUNK, E);
    int n4 = (end - start) >> 2;           // chunk sizes divisible by 4
    const uint4* d4p = (const uint4*)(dst + start);
    for (int i = t; i < n4; i += BT) {
        uint4 d = d4p[i];
        atomicAdd(&h[d.x >> BUCKET_BITS], 1u);
        atomicAdd(&h[d.y >> BUCKET_BITS], 1u);
        atomicAdd(&h[d.z >> BUCKET_BITS], 1u);
        atomicAdd(&h[d.w >> BUCKET_BITS], 1u);
    }
    __syncthreads();
    if (t < nbuck) part[(size_t)c * nbuck + t] = h[t];
}

// K2: per-bucket exclusive prefix across chunks (in place); totals -> cnt[j]
__global__ void colscan_kernel(u32* __restrict__ part, u32* __restrict__ cnt,
                               int NB, int nbuck) {
    __shared__ u32 s[MAX_NB];
    int t = threadIdx.x, j = blockIdx.x;  // 1024 threads, j < nbuck
    u32 v = (t < NB) ? part[(size_t)t * nbuck + j] : 0u;
    s[t] = v;
    for (int o = 1; o < MAX_NB; o <<= 1) {
        __syncthreads();
        u32 u = (t >= o) ? s[t - o] : 0u;
        __syncthreads();
        s[t] += u;
    }
    __syncthreads();
    if (t < NB) part[(size_t)t * nbuck + j] = s[t] - v;  // exclusive prefix
    if (t == MAX_NB - 1) cnt[j] = s[MAX_NB - 1];         // bucket total
}

// K3: exclusive scan of bucket totals -> offsets[0..nbuck]
__global__ void offsets_kernel(const u32* __restrict__ cnt, u32* __restrict__ offsets,
                               int nbuck) {
    __shared__ u32 s[MAX_NBUCK];
    int t = threadIdx.x;  // 512
    u32 v = (t < nbuck) ? cnt[t] : 0u;
    s[t] = v;
    for (int o = 1; o < MAX_NBUCK; o <<= 1) {
        __syncthreads();
        u32 u = (t >= o) ? s[t - o] : 0u;
        __syncthreads();
        s[t] += u;
    }
    __syncthreads();
    if (t < nbuck) offsets[t + 1] = s[t];
    if (t == 0) offsets[0] = 0;
}

// Block-wide exclusive scan over BT=1024 threads (16 waves, 2 barriers)
__device__ __forceinline__ u32 block_exscan16(u32 v, u32* wtot /*>=16 u32 LDS*/) {
    int t = threadIdx.x, lane = t & 63, wid = t >> 6;
    u32 x = v;
#pragma unroll
    for (int d = 1; d < 64; d <<= 1) {
        u32 u = __shfl_up(x, d);
        if (lane >= d) x += u;
    }
    if (lane == 63) wtot[wid] = x;
    __syncthreads();
    u32 woff = 0;
#pragma unroll
    for (int w = 0; w < 16; ++w) {
        u32 wv = wtot[w];
        woff += (w < wid) ? wv : 0u;
    }
    __syncthreads();   // wtot reusable after this
    return woff + x - v;
}

// K4: LDS-reorder scatter. Chunk counts from part; 16-wave shuffle scan;
// packed lbase<<16|rank; uint4 src/dst loads; bk u16 + dadj stream-out.
__global__ void __launch_bounds__(BT)
scatter_kernel(const int* __restrict__ src, const int* __restrict__ dst,
               const u32* __restrict__ part, const u32* __restrict__ cnt,
               const u32* __restrict__ offsets, u32* __restrict__ sorted,
               int E, int nbuck, int NB) {
    __shared__ u32 pk[PCHUNK];        // 32KB packed edges, bucket-ordered
    __shared__ u16 bk[PCHUNK];        // 16KB bucket id per slot
    __shared__ u32 scr[MAX_NBUCK];    // 2KB: (lbase<<16) | rank
    __shared__ u32 dadj[MAX_NBUCK];   // 2KB: global_base - lbase
    __shared__ u32 wtot[16];
    int t = threadIdx.x, c = blockIdx.x;
    int start = c * PCHUNK, end = min(start + PCHUNK, E);
    int cntE = end - start;

    u32 v = 0, gb = 0;
    if (t < nbuck) {
        u32 pc = part[(size_t)c * nbuck + t];
        u32 nx = (c + 1 < NB) ? part[(size_t)(c + 1) * nbuck + t] : cnt[t];
        v = nx - pc;
        gb = offsets[t] + pc;
    }
    u32 lb = block_exscan16(v, wtot);
    if (t < MAX_NBUCK) {
        scr[t] = lb << 16;             // rank starts at 0
        dadj[t] = gb - lb;             // only consulted for t < nbuck
    }
    __syncthreads();
    int n4 = cntE >> 2;                // chunk sizes divisible by 4
    const uint4* s4p = (const uint4*)(src + start);
    const uint4* d4p = (const uint4*)(dst + start);
    for (int i = t; i < n4; i += BT) {
        uint4 s4 = s4p[i];
        uint4 d4 = d4p[i];
        u32 b0 = d4.x >> BUCKET_BITS, b1 = d4.y >> BUCKET_BITS;
        u32 b2 = d4.z >> BUCKET_BITS, b3 = d4.w >> BUCKET_BITS;
        u32 o0 = atomicAdd(&scr[b0], 1u);
        u32 p0 = (o0 >> 16) + (o0 & 0xFFFFu);
        pk[p0] = (s4.x << BUCKET_BITS) | (d4.x & (BUCKET_SIZE - 1)); bk[p0] = (u16)b0;
        u32 o1 = atomicAdd(&scr[b1], 1u);
        u32 p1 = (o1 >> 16) + (o1 & 0xFFFFu);
        pk[p1] = (s4.y << BUCKET_BITS) | (d4.y & (BUCKET_SIZE - 1)); bk[p1] = (u16)b1;
        u32 o2 = atomicAdd(&scr[b2], 1u);
        u32 p2 = (o2 >> 16) + (o2 & 0xFFFFu);
        pk[p2] = (s4.z << BUCKET_BITS) | (d4.z & (BUCKET_SIZE - 1)); bk[p2] = (u16)b2;
        u32 o3 = atomicAdd(&scr[b3], 1u);
        u32 p3 = (o3 >> 16) + (o3 & 0xFFFFu);
        pk[p3] = (s4.w << BUCKET_BITS) | (d4.w & (BUCKET_SIZE - 1)); bk[p3] = (u16)b3;
    }
    __syncthreads();
    for (int i = t; i < cntE; i += BT)
        sorted[dadj[bk[i]] + i] = pk[i];
}

// K5: per-bucket second-level counting sort, SINGLE global read: stage into
// buf during count, place buf->buf2 in LDS, coalesced stream-out. ~138KB LDS.
__global__ void __launch_bounds__(BT)
sort2_kernel(u32* __restrict__ sorted /* in: packed; out: ssrc */,
             const u32* __restrict__ offsets, const float2* __restrict__ x,
             u32* __restrict__ noff, float* __restrict__ dinv,
             float2* __restrict__ y, int N) {
    __shared__ u32 buf[LDSCAP];        // 68 KB staged packed edges
    __shared__ u32 buf2[LDSCAP];       // 68 KB src values, node-run order
    __shared__ u32 cnt[BUCKET_SIZE];   // per-local-dst count -> cursor
    __shared__ u32 wtot[16];
    int t = threadIdx.x, b = blockIdx.x;
    u32 e0 = offsets[b];
    u32 len = offsets[b + 1] - e0;
    if (len > LDSCAP) len = LDSCAP;    // safety only; Poisson tail ~0

    if (t < BUCKET_SIZE) cnt[t] = 0;
    __syncthreads();
    // Pass 1: read once (coalesced), stage, count
    for (u32 i = t; i < len; i += BT) {
        u32 e = sorted[e0 + i];
        buf[i] = e;
        atomicAdd(&cnt[e & (BUCKET_SIZE - 1)], 1u);
    }
    __syncthreads();
    u32 v = (t < BUCKET_SIZE) ? cnt[t] : 0u;
    u32 lb = block_exscan16(v, wtot);
    int node = (b << BUCKET_BITS) + t;
    if (t < BUCKET_SIZE && node < N) {
        noff[node] = e0 + lb;
        float di = rsqrtf((float)v + 1.0f);  // +1 self-loop
        dinv[node] = di;
        float2 xv = x[node];
        y[node] = make_float2(di * xv.x, di * xv.y);
    }
    if (t < BUCKET_SIZE) cnt[t] = lb;  // reuse as placement cursor
    __syncthreads();
    // Pass 2: LDS -> LDS place (no global traffic)
    for (u32 i = t; i < len; i += BT) {
        u32 e = buf[i];
        u32 p = atomicAdd(&cnt[e & (BUCKET_SIZE - 1)], 1u);
        buf2[p] = e >> BUCKET_BITS;
    }
    __syncthreads();
    // Pass 3: coalesced stream-out
    for (u32 i = t; i < len; i += BT)
        sorted[e0 + i] = buf2[i];
}

// K6: layer-1 aggregation, 8 lanes per node + __shfl_xor combine + fused MLP
__global__ void __launch_bounds__(256)
agg1_mlp_kernel(const u32* __restrict__ ssrc, const u32* __restrict__ noff,
                const float2* __restrict__ y, const float* __restrict__ dinv,
                const float* __restrict__ W1, const float* __restrict__ b1,
                const float* __restrict__ W2,
                float2* __restrict__ gp, int N, u32 E) {
    int tid = blockIdx.x * blockDim.x + threadIdx.x;
    int node = tid >> 3, sub = tid & 7;
    if (node >= N) return;
    u32 i0 = noff[node];
    u32 e1 = (node + 1 < N) ? noff[node + 1] : E;
    u32 len = e1 - i0;
    u32 i = i0 + (len * (u32)sub) / 8;
    u32 q1 = i0 + (len * (u32)(sub + 1)) / 8;
    float sx = 0.f, sy = 0.f;
    for (; i + 4 <= q1; i += 4) {
        u32 s0 = ssrc[i], s1 = ssrc[i + 1], s2 = ssrc[i + 2], s3 = ssrc[i + 3];
        float2 v0 = y[s0], v1 = y[s1], v2 = y[s2], v3 = y[s3];
        sx += (v0.x + v1.x) + (v2.x + v3.x);
        sy += (v0.y + v1.y) + (v2.y + v3.y);
    }
    for (; i < q1; ++i) {
        float2 v = y[ssrc[i]];
        sx += v.x; sy += v.y;
    }
    sx += __shfl_xor(sx, 1); sy += __shfl_xor(sy, 1);
    sx += __shfl_xor(sx, 2); sy += __shfl_xor(sy, 2);
    sx += __shfl_xor(sx, 4); sy += __shfl_xor(sy, 4);
    if (sub == 0) {
        float2 yv = y[node];
        float di = dinv[node];
        float ax = di * (sx + yv.x), ay = di * (sy + yv.y);
        float g0 = 0.f, g1 = 0.f;
#pragma unroll
        for (int j = 0; j < 16; ++j) {
            float h = fmaf(ax, W1[j], fmaf(ay, W1[16 + j], b1[j]));
            h = fmaxf(h, 0.f);
            g0 = fmaf(h, W2[2 * j], g0);
            g1 = fmaf(h, W2[2 * j + 1], g1);
        }
        gp[node] = make_float2(di * g0, di * g1);
    }
}

// K7: layer-2 aggregation, 8 lanes per node + __shfl_xor combine
__global__ void __launch_bounds__(256)
agg2_kernel(const u32* __restrict__ ssrc, const u32* __restrict__ noff,
            const float2* __restrict__ gp, const float* __restrict__ dinv,
            const float* __restrict__ b2, float2* __restrict__ out, int N, u32 E) {
    int tid = blockIdx.x * blockDim.x + threadIdx.x;
    int node = tid >> 3, sub = tid & 7;
    if (node >= N) return;
    u32 i0 = noff[node];
    u32 e1 = (node + 1 < N) ? noff[node + 1] : E;
    u32 len = e1 - i0;
    u32 i = i0 + (len * (u32)sub) / 8;
    u32 q1 = i0 + (len * (u32)(sub + 1)) / 8;
    float sx = 0.f, sy = 0.f;
    for (; i + 4 <= q1; i += 4) {
        u32 s0 = ssrc[i], s1 = ssrc[i + 1], s2 = ssrc[i + 2], s3 = ssrc[i + 3];
        float2 v0 = gp[s0], v1 = gp[s1], v2 = gp[s2], v3 = gp[s3];
        sx += (v0.x + v1.x) + (v2.x + v3.x);
        sy += (v0.y + v1.y) + (v2.y + v3.y);
    }
    for (; i < q1; ++i) {
        float2 v = gp[ssrc[i]];
        sx += v.x; sy += v.y;
    }
    sx += __shfl_xor(sx, 1); sy += __shfl_xor(sy, 1);
    sx += __shfl_xor(sx, 2); sy += __shfl_xor(sy, 2);
    sx += __shfl_xor(sx, 4); sy += __shfl_xor(sy, 4);
    if (sub == 0) {
        float2 gv = gp[node];
        float di = dinv[node];
        out[node] = make_float2(fmaf(di, sx + gv.x, b2[0]),
                                fmaf(di, sy + gv.y, b2[1]));
    }
}

extern "C" void kernel_launch(void* const* d_in, const int* in_sizes, int n_in,
                              void* d_out, int out_size, void* d_ws, size_t ws_size,
                              hipStream_t stream) {
    const float2* x  = (const float2*)d_in[0];
    const int*    ei = (const int*)d_in[1];   // [2, E]: src row then dst row
    const float*  W1 = (const float*)d_in[2];
    const float*  b1 = (const float*)d_in[3];
    const float*  W2 = (const float*)d_in[4];
    const float*  b2 = (const float*)d_in[5];

    const int N = in_sizes[0] / 2;
    const int E = in_sizes[1] / 2;
    const int* src = ei;
    const int* dst = ei + E;
    const int nbuck = (N + BUCKET_SIZE - 1) >> BUCKET_BITS;   // 391
    const int NB    = (E + PCHUNK - 1) / PCHUNK;              // 782 (<= 1024)

    // Workspace (~31MB). `part` aliases y (dead before sort2 writes y);
    // `sorted` overwritten in place by sort2 to become `ssrc`.
    u32* sorted   = (u32*)d_ws;                               // E (-> ssrc)
    float* dinv   = (float*)(sorted + E);                     // N
    float* y      = dinv + N;                                 // 2N
    float* gp     = y + 2 * (size_t)N;                        // 2N
    u32* noff     = (u32*)(gp + 2 * (size_t)N);               // N
    u32* cnt      = noff + N;                                 // 512
    u32* offsets  = cnt + MAX_NBUCK;                          // nbuck+1
    u32* part     = (u32*)y;                                  // alias
    float2* out   = (float2*)d_out;

    part_hist_kernel<<<NB, BT, 0, stream>>>(dst, part, E, nbuck);
    colscan_kernel  <<<nbuck, MAX_NB, 0, stream>>>(part, cnt, NB, nbuck);
    offsets_kernel  <<<1, MAX_NBUCK, 0, stream>>>(cnt, offsets, nbuck);
    scatter_kernel  <<<NB, BT, 0, stream>>>(src, dst, part, cnt, offsets,
                                            sorted, E, nbuck, NB);
    sort2_kernel    <<<nbuck, BT, 0, stream>>>(sorted, offsets, x, noff, dinv,
                                               (float2*)y, N);
    agg1_mlp_kernel <<<(8 * N + 255) / 256, 256, 0, stream>>>(sorted, noff,
                                                              (const float2*)y, dinv,
                                                              W1, b1, W2,
                                                              (float2*)gp, N, (u32)E);
    agg2_kernel     <<<(8 * N + 255) / 256, 256, 0, stream>>>(sorted, noff,
                                                              (const float2*)gp, dinv,
                                                              b2, out, N, (u32)E);
}

// Round 23
// 122.760 us; speedup vs baseline: 1.0466x; 1.0466x over previous
//
#include <hip/hip_runtime.h>

// GCN 2-layer, fully-deterministic two-level sort + register aggregation.
// History: global fp32 atomics EA-bound (r1-2); bucket sort + LDS atomics
// (r5-14); two-level sort + lane-per-node register agg (r15-20, 127us);
// r21/22 trims neutral (sort2 138KB-LDS variant cost its own saving at
// 1 block/CU). Round-23: revert sort2 to the 70KB two-read form (2 blocks/CU);
// delete offsets_kernel -- scatter/sort2 recompute exscan(cnt) locally with
// the existing 2-barrier wave-shuffle scan (one fewer dispatch).
// All buffers remain pure functions of the inputs (replay-deterministic).

typedef unsigned int u32;
typedef unsigned short u16;

#define BUCKET_BITS 9
#define BUCKET_SIZE (1 << BUCKET_BITS)   // 512 nodes per bucket
#define MAX_NBUCK 512                    // supports N <= 262144
#define PCHUNK 8192                      // edges per partition chunk
#define BT 1024                          // big-block threads
#define MAX_NB 1024                      // supports E <= 8.4M
#define LDSCAP 17408                     // max edges staged per bucket (68KB)

// K1: per-chunk bucket histogram -> part[c*nbuck + j]  (uint4 loads)
__global__ void __launch_bounds__(BT)
part_hist_kernel(const int* __restrict__ dst, u32* __restrict__ part,
                 int E, int nbuck) {
    __shared__ u32 h[MAX_NBUCK];
    int t = threadIdx.x, c = blockIdx.x;
    if (t < MAX_NBUCK) h[t] = 0;
    __syncthreads();
    int start = c * PCHUNK, end = min(start + PCHUNK, E);
    int n4 = (end - start) >> 2;           // chunk sizes divisible by 4
    const uint4* d4p = (const uint4*)(dst + start);
    for (int i = t; i < n4; i += BT) {
        uint4 d = d4p[i];
        atomicAdd(&h[d.x >> BUCKET_BITS], 1u);
        atomicAdd(&h[d.y >> BUCKET_BITS], 1u);
        atomicAdd(&h[d.z >> BUCKET_BITS], 1u);
        atomicAdd(&h[d.w >> BUCKET_BITS], 1u);
    }
    __syncthreads();
    if (t < nbuck) part[(size_t)c * nbuck + t] = h[t];
}

// K2: per-bucket exclusive prefix across chunks (in place); totals -> cnt[j]
__global__ void colscan_kernel(u32* __restrict__ part, u32* __restrict__ cnt,
                               int NB, int nbuck) {
    __shared__ u32 s[MAX_NB];
    int t = threadIdx.x, j = blockIdx.x;  // 1024 threads, j < nbuck
    u32 v = (t < NB) ? part[(size_t)t * nbuck + j] : 0u;
    s[t] = v;
    for (int o = 1; o < MAX_NB; o <<= 1) {
        __syncthreads();
        u32 u = (t >= o) ? s[t - o] : 0u;
        __syncthreads();
        s[t] += u;
    }
    __syncthreads();
    if (t < NB) part[(size_t)t * nbuck + j] = s[t] - v;  // exclusive prefix
    if (t == MAX_NB - 1) cnt[j] = s[MAX_NB - 1];         // bucket total
}

// Block-wide exclusive scan over BT=1024 threads (16 waves, 2 barriers)
__device__ __forceinline__ u32 block_exscan16(u32 v, u32* wtot /*>=16 u32 LDS*/) {
    int t = threadIdx.x, lane = t & 63, wid = t >> 6;
    u32 x = v;
#pragma unroll
    for (int d = 1; d < 64; d <<= 1) {
        u32 u = __shfl_up(x, d);
        if (lane >= d) x += u;
    }
    if (lane == 63) wtot[wid] = x;
    __syncthreads();
    u32 woff = 0;
#pragma unroll
    for (int w = 0; w < 16; ++w) {
        u32 wv = wtot[w];
        woff += (w < wid) ? wv : 0u;
    }
    __syncthreads();   // wtot reusable after this
    return woff + x - v;
}

// K3: LDS-reorder scatter. Chunk counts from part; bucket offsets computed
// in-block as exscan(cnt); packed lbase<<16|rank; uint4 loads; u16 bk + dadj.
__global__ void __launch_bounds__(BT)
scatter_kernel(const int* __restrict__ src, const int* __restrict__ dst,
               const u32* __restrict__ part, const u32* __restrict__ cnt,
               u32* __restrict__ sorted, int E, int nbuck, int NB) {
    __shared__ u32 pk[PCHUNK];        // 32KB packed edges, bucket-ordered
    __shared__ u16 bk[PCHUNK];        // 16KB bucket id per slot
    __shared__ u32 scr[MAX_NBUCK];    // 2KB: (lbase<<16) | rank
    __shared__ u32 dadj[MAX_NBUCK];   // 2KB: global_base - lbase
    __shared__ u32 wtot[16];
    int t = threadIdx.x, c = blockIdx.x;
    int start = c * PCHUNK, end = min(start + PCHUNK, E);
    int cntE = end - start;

    // bucket global offsets: exscan of cnt (recomputed per block, 2 barriers)
    u32 cv = (t < nbuck) ? cnt[t] : 0u;
    u32 offT = block_exscan16(cv, wtot);   // = offsets[t] for t < nbuck

    u32 v = 0, gb = 0;
    if (t < nbuck) {
        u32 pc = part[(size_t)c * nbuck + t];
        u32 nx = (c + 1 < NB) ? part[(size_t)(c + 1) * nbuck + t] : cnt[t];
        v = nx - pc;
        gb = offT + pc;
    }
    u32 lb = block_exscan16(v, wtot);
    if (t < MAX_NBUCK) {
        scr[t] = lb << 16;             // rank starts at 0
        dadj[t] = gb - lb;             // only consulted for t < nbuck
    }
    __syncthreads();
    int n4 = cntE >> 2;                // chunk sizes divisible by 4
    const uint4* s4p = (const uint4*)(src + start);
    const uint4* d4p = (const uint4*)(dst + start);
    for (int i = t; i < n4; i += BT) {
        uint4 s4 = s4p[i];
        uint4 d4 = d4p[i];
        u32 b0 = d4.x >> BUCKET_BITS, b1 = d4.y >> BUCKET_BITS;
        u32 b2 = d4.z >> BUCKET_BITS, b3 = d4.w >> BUCKET_BITS;
        u32 o0 = atomicAdd(&scr[b0], 1u);
        u32 p0 = (o0 >> 16) + (o0 & 0xFFFFu);
        pk[p0] = (s4.x << BUCKET_BITS) | (d4.x & (BUCKET_SIZE - 1)); bk[p0] = (u16)b0;
        u32 o1 = atomicAdd(&scr[b1], 1u);
        u32 p1 = (o1 >> 16) + (o1 & 0xFFFFu);
        pk[p1] = (s4.y << BUCKET_BITS) | (d4.y & (BUCKET_SIZE - 1)); bk[p1] = (u16)b1;
        u32 o2 = atomicAdd(&scr[b2], 1u);
        u32 p2 = (o2 >> 16) + (o2 & 0xFFFFu);
        pk[p2] = (s4.z << BUCKET_BITS) | (d4.z & (BUCKET_SIZE - 1)); bk[p2] = (u16)b2;
        u32 o3 = atomicAdd(&scr[b3], 1u);
        u32 p3 = (o3 >> 16) + (o3 & 0xFFFFu);
        pk[p3] = (s4.w << BUCKET_BITS) | (d4.w & (BUCKET_SIZE - 1)); bk[p3] = (u16)b3;
    }
    __syncthreads();
    for (int i = t; i < cntE; i += BT)
        sorted[dadj[bk[i]] + i] = pk[i];
}

// K4: per-bucket second-level counting sort (r20 70KB two-read form);
// bucket base e0 computed in-block from exscan(cnt). Emits noff, dinv, y.
__global__ void __launch_bounds__(BT)
sort2_kernel(u32* __restrict__ sorted /* in: packed; out: ssrc */,
             const u32* __restrict__ cnt_g, const float2* __restrict__ x,
             u32* __restrict__ noff, float* __restrict__ dinv,
             float2* __restrict__ y, int N, int nbuck) {
    __shared__ u32 buf[LDSCAP];        // 68 KB: src values, node-run order
    __shared__ u32 cnt[BUCKET_SIZE];   // per-local-dst count -> cursor
    __shared__ u32 wtot[16];
    __shared__ u32 e0s;
    int t = threadIdx.x, b = blockIdx.x;

    // e0 = offsets[b] = exscan(cnt_g)[b]; len = cnt_g[b]
    u32 cv = (t < nbuck) ? cnt_g[t] : 0u;
    u32 offT = block_exscan16(cv, wtot);
    if (t == b) e0s = offT;            // b < nbuck <= 512 < BT
    __syncthreads();
    u32 e0 = e0s;
    u32 len = cnt_g[b];
    if (len > LDSCAP) len = LDSCAP;    // safety only; Poisson tail ~0

    if (t < BUCKET_SIZE) cnt[t] = 0;
    __syncthreads();
    for (u32 i = t; i < len; i += BT)
        atomicAdd(&cnt[sorted[e0 + i] & (BUCKET_SIZE - 1)], 1u);
    __syncthreads();
    u32 v = (t < BUCKET_SIZE) ? cnt[t] : 0u;
    u32 lb = block_exscan16(v, wtot);
    int node = (b << BUCKET_BITS) + t;
    if (t < BUCKET_SIZE && node < N) {
        noff[node] = e0 + lb;
        float di = rsqrtf((float)v + 1.0f);  // +1 self-loop
        dinv[node] = di;
        float2 xv = x[node];
        y[node] = make_float2(di * xv.x, di * xv.y);
    }
    if (t < BUCKET_SIZE) cnt[t] = lb;  // reuse as placement cursor
    __syncthreads();
    for (u32 i = t; i < len; i += BT) {
        u32 e = sorted[e0 + i];
        u32 p = atomicAdd(&cnt[e & (BUCKET_SIZE - 1)], 1u);
        buf[p] = e >> BUCKET_BITS;
    }
    __syncthreads();
    for (u32 i = t; i < len; i += BT)
        sorted[e0 + i] = buf[i];
}

// K5: layer-1 aggregation, 8 lanes per node + __shfl_xor combine + fused MLP
__global__ void __launch_bounds__(256)
agg1_mlp_kernel(const u32* __restrict__ ssrc, const u32* __restrict__ noff,
                const float2* __restrict__ y, const float* __restrict__ dinv,
                const float* __restrict__ W1, const float* __restrict__ b1,
                const float* __restrict__ W2,
                float2* __restrict__ gp, int N, u32 E) {
    int tid = blockIdx.x * blockDim.x + threadIdx.x;
    int node = tid >> 3, sub = tid & 7;
    if (node >= N) return;
    u32 i0 = noff[node];
    u32 e1 = (node + 1 < N) ? noff[node + 1] : E;
    u32 len = e1 - i0;
    u32 i = i0 + (len * (u32)sub) / 8;
    u32 q1 = i0 + (len * (u32)(sub + 1)) / 8;
    float sx = 0.f, sy = 0.f;
    for (; i + 4 <= q1; i += 4) {
        u32 s0 = ssrc[i], s1 = ssrc[i + 1], s2 = ssrc[i + 2], s3 = ssrc[i + 3];
        float2 v0 = y[s0], v1 = y[s1], v2 = y[s2], v3 = y[s3];
        sx += (v0.x + v1.x) + (v2.x + v3.x);
        sy += (v0.y + v1.y) + (v2.y + v3.y);
    }
    for (; i < q1; ++i) {
        float2 v = y[ssrc[i]];
        sx += v.x; sy += v.y;
    }
    sx += __shfl_xor(sx, 1); sy += __shfl_xor(sy, 1);
    sx += __shfl_xor(sx, 2); sy += __shfl_xor(sy, 2);
    sx += __shfl_xor(sx, 4); sy += __shfl_xor(sy, 4);
    if (sub == 0) {
        float2 yv = y[node];
        float di = dinv[node];
        float ax = di * (sx + yv.x), ay = di * (sy + yv.y);
        float g0 = 0.f, g1 = 0.f;
#pragma unroll
        for (int j = 0; j < 16; ++j) {
            float h = fmaf(ax, W1[j], fmaf(ay, W1[16 + j], b1[j]));
            h = fmaxf(h, 0.f);
            g0 = fmaf(h, W2[2 * j], g0);
            g1 = fmaf(h, W2[2 * j + 1], g1);
        }
        gp[node] = make_float2(di * g0, di * g1);
    }
}

// K6: layer-2 aggregation, 8 lanes per node + __shfl_xor combine
__global__ void __launch_bounds__(256)
agg2_kernel(const u32* __restrict__ ssrc, const u32* __restrict__ noff,
            const float2* __restrict__ gp, const float* __restrict__ dinv,
            const float* __restrict__ b2, float2* __restrict__ out, int N, u32 E) {
    int tid = blockIdx.x * blockDim.x + threadIdx.x;
    int node = tid >> 3, sub = tid & 7;
    if (node >= N) return;
    u32 i0 = noff[node];
    u32 e1 = (node + 1 < N) ? noff[node + 1] : E;
    u32 len = e1 - i0;
    u32 i = i0 + (len * (u32)sub) / 8;
    u32 q1 = i0 + (len * (u32)(sub + 1)) / 8;
    float sx = 0.f, sy = 0.f;
    for (; i + 4 <= q1; i += 4) {
        u32 s0 = ssrc[i], s1 = ssrc[i + 1], s2 = ssrc[i + 2], s3 = ssrc[i + 3];
        float2 v0 = gp[s0], v1 = gp[s1], v2 = gp[s2], v3 = gp[s3];
        sx += (v0.x + v1.x) + (v2.x + v3.x);
        sy += (v0.y + v1.y) + (v2.y + v3.y);
    }
    for (; i < q1; ++i) {
        float2 v = gp[ssrc[i]];
        sx += v.x; sy += v.y;
    }
    sx += __shfl_xor(sx, 1); sy += __shfl_xor(sy, 1);
    sx += __shfl_xor(sx, 2); sy += __shfl_xor(sy, 2);
    sx += __shfl_xor(sx, 4); sy += __shfl_xor(sy, 4);
    if (sub == 0) {
        float2 gv = gp[node];
        float di = dinv[node];
        out[node] = make_float2(fmaf(di, sx + gv.x, b2[0]),
                                fmaf(di, sy + gv.y, b2[1]));
    }
}

extern "C" void kernel_launch(void* const* d_in, const int* in_sizes, int n_in,
                              void* d_out, int out_size, void* d_ws, size_t ws_size,
                              hipStream_t stream) {
    const float2* x  = (const float2*)d_in[0];
    const int*    ei = (const int*)d_in[1];   // [2, E]: src row then dst row
    const float*  W1 = (const float*)d_in[2];
    const float*  b1 = (const float*)d_in[3];
    const float*  W2 = (const float*)d_in[4];
    const float*  b2 = (const float*)d_in[5];

    const int N = in_sizes[0] / 2;
    const int E = in_sizes[1] / 2;
    const int* src = ei;
    const int* dst = ei + E;
    const int nbuck = (N + BUCKET_SIZE - 1) >> BUCKET_BITS;   // 391
    const int NB    = (E + PCHUNK - 1) / PCHUNK;              // 782 (<= 1024)

    // Workspace (~31MB). `part` aliases y (dead before sort2 writes y);
    // `sorted` overwritten in place by sort2 to become `ssrc`.
    u32* sorted   = (u32*)d_ws;                               // E (-> ssrc)
    float* dinv   = (float*)(sorted + E);                     // N
    float* y      = dinv + N;                                 // 2N
    float* gp     = y + 2 * (size_t)N;                        // 2N
    u32* noff     = (u32*)(gp + 2 * (size_t)N);               // N
    u32* cnt      = noff + N;                                 // 512
    u32* part     = (u32*)y;                                  // alias
    float2* out   = (float2*)d_out;

    part_hist_kernel<<<NB, BT, 0, stream>>>(dst, part, E, nbuck);
    colscan_kernel  <<<nbuck, MAX_NB, 0, stream>>>(part, cnt, NB, nbuck);
    scatter_kernel  <<<NB, BT, 0, stream>>>(src, dst, part, cnt,
                                            sorted, E, nbuck, NB);
    sort2_kernel    <<<nbuck, BT, 0, stream>>>(sorted, cnt, x, noff, dinv,
                                               (float2*)y, N, nbuck);
    agg1_mlp_kernel <<<(8 * N + 255) / 256, 256, 0, stream>>>(sorted, noff,
                                                              (const float2*)y, dinv,
                                                              W1, b1, W2,
                                                              (float2*)gp, N, (u32)E);
    agg2_kernel     <<<(8 * N + 255) / 256, 256, 0, stream>>>(sorted, noff,
                                                              (const float2*)gp, dinv,
                                                              b2, out, N, (u32)E);
}